// Round 6
// baseline (1089.820 us; speedup 1.0000x reference)
//
#include <hip/hip_runtime.h>
#include <hip/hip_bf16.h>

typedef __bf16 bf16;
typedef __bf16 bf16x8 __attribute__((ext_vector_type(8)));
typedef __bf16 bf16x4 __attribute__((ext_vector_type(4)));
typedef float f32x4_t __attribute__((ext_vector_type(4)));

static constexpr int kDIM = 512;

// ---------------- ws layout (bytes) ----------------
static constexpr size_t OFF_QKVW = 0;                         // 1536*512 bf16
static constexpr size_t OFF_PROJW = 1572864;                  // 512*512 bf16
static constexpr size_t OFF_W1   = 2097152;                   // 2048*512 bf16
static constexpr size_t OFF_W2   = 4194304;                   // 512*2048 bf16
static constexpr size_t OFF_PTAB = 6291456;                   // 225*16 f32
static constexpr size_t OFF_A    = 8388608;                   // qkv / hidden bf16
static constexpr size_t OFF_B    = 276824064;                 // h / o / ln2out bf16

typedef __attribute__((address_space(3))) uint32_t lds_u32_t;
typedef __attribute__((address_space(1))) const uint32_t glb_u32_t;
#define ASYNC_COPY16(gp, lp) __builtin_amdgcn_global_load_lds((glb_u32_t*)(gp), (lds_u32_t*)(lp), 16, 0, 0)

// ---------------- fp32 -> bf16 cast ----------------
__global__ void cast_bf16_k(const float* __restrict__ in, bf16* __restrict__ out, int n4)
{
    int i = blockIdx.x * blockDim.x + threadIdx.x;
    if (i < n4) {
        float4 v = ((const float4*)in)[i];
        bf16x4 o; o[0] = (bf16)v.x; o[1] = (bf16)v.y; o[2] = (bf16)v.z; o[3] = (bf16)v.w;
        ((bf16x4*)out)[i] = o;
    }
}

// ---------------- LayerNorm (+ optional LDA grouping) -> bf16 ----------------
template<int GROUP>
__global__ __launch_bounds__(256)
void ln_k(const float* __restrict__ x, const float* __restrict__ gw,
          const float* __restrict__ bw, bf16* __restrict__ out)
{
    const int t = blockIdx.x * 4 + (threadIdx.x >> 6);
    const int lane = threadIdx.x & 63;
    const float* xp = x + (size_t)t * kDIM + lane * 8;
    float4 p0 = *(const float4*)xp;
    float4 p1 = *(const float4*)(xp + 4);
    float v[8] = {p0.x, p0.y, p0.z, p0.w, p1.x, p1.y, p1.z, p1.w};
    float s = 0.f;
#pragma unroll
    for (int i = 0; i < 8; ++i) s += v[i];
#pragma unroll
    for (int off = 32; off > 0; off >>= 1) s += __shfl_xor(s, off);
    const float mean = s * (1.0f / 512.0f);
    float q = 0.f;
#pragma unroll
    for (int i = 0; i < 8; ++i) { float d = v[i] - mean; q += d * d; }
#pragma unroll
    for (int off = 32; off > 0; off >>= 1) q += __shfl_xor(q, off);
    const float rstd = rsqrtf(q * (1.0f / 512.0f) + 1e-5f);
    size_t orow;
    if (GROUP) {
        int b = t >> 12, r = (t >> 6) & 63, c = t & 63;
        int g = b * 64 + (r & 7) * 8 + (c & 7);
        int n = (r >> 3) * 8 + (c >> 3);
        orow = (size_t)g * 64 + n;
    } else {
        orow = t;
    }
    float4 g0 = *(const float4*)(gw + lane * 8);
    float4 g1 = *(const float4*)(gw + lane * 8 + 4);
    float4 b0 = *(const float4*)(bw + lane * 8);
    float4 b1 = *(const float4*)(bw + lane * 8 + 4);
    float gg[8] = {g0.x, g0.y, g0.z, g0.w, g1.x, g1.y, g1.z, g1.w};
    float bb[8] = {b0.x, b0.y, b0.z, b0.w, b1.x, b1.y, b1.z, b1.w};
    bf16x8 o8;
#pragma unroll
    for (int i = 0; i < 8; ++i) o8[i] = (bf16)((v[i] - mean) * rstd * gg[i] + bb[i]);
    *(bf16x8*)(out + orow * kDIM + lane * 8) = o8;
}

// ---------------- dynamic position bias MLP: 225 rows, 2->32->32->32->16 ----------------
__device__ inline void ln32_relu(float* h, const float* g, const float* b)
{
    float m = 0.f;
#pragma unroll
    for (int i = 0; i < 32; ++i) m += h[i];
    m *= (1.0f / 32.0f);
    float v = 0.f;
#pragma unroll
    for (int i = 0; i < 32; ++i) { float d = h[i] - m; v += d * d; }
    v *= (1.0f / 32.0f);
    float r = rsqrtf(v + 1e-5f);
#pragma unroll
    for (int i = 0; i < 32; ++i) h[i] = fmaxf((h[i] - m) * r * g[i] + b[i], 0.f);
}

__global__ __launch_bounds__(256)
void posmlp_k(const float* __restrict__ w0, const float* __restrict__ b0,
              const float* __restrict__ g0, const float* __restrict__ bb0,
              const float* __restrict__ w1, const float* __restrict__ b1,
              const float* __restrict__ g1, const float* __restrict__ bb1,
              const float* __restrict__ w2, const float* __restrict__ b2,
              const float* __restrict__ g2, const float* __restrict__ bb2,
              const float* __restrict__ w3, const float* __restrict__ b3,
              float* __restrict__ ptab)
{
    int r = threadIdx.x;
    if (r >= 225) return;
    float in0 = (float)(r / 15) - 7.0f;
    float in1 = (float)(r % 15) - 7.0f;
    float h[32], h2[32];
#pragma unroll
    for (int o = 0; o < 32; ++o) h[o] = w0[o * 2] * in0 + w0[o * 2 + 1] * in1 + b0[o];
    ln32_relu(h, g0, bb0);
#pragma unroll
    for (int o = 0; o < 32; ++o) {
        float s = b1[o];
#pragma unroll
        for (int i = 0; i < 32; ++i) s += w1[o * 32 + i] * h[i];
        h2[o] = s;
    }
    ln32_relu(h2, g1, bb1);
#pragma unroll
    for (int o = 0; o < 32; ++o) {
        float s = b2[o];
#pragma unroll
        for (int i = 0; i < 32; ++i) s += w2[o * 32 + i] * h2[i];
        h[o] = s;
    }
    ln32_relu(h, g2, bb2);
#pragma unroll
    for (int o = 0; o < 16; ++o) {
        float s = b3[o];
#pragma unroll
        for (int i = 0; i < 32; ++i) s += w3[o * 32 + i] * h[i];
        ptab[r * 16 + o] = s;
    }
}

// ---------------- attention via MFMA: block = (group, head-octet), 4 waves x 2 heads ----------------
__global__ __launch_bounds__(256)
void attn_mfma_k(const bf16* __restrict__ qkv, const float* __restrict__ ptab,
                 bf16* __restrict__ obuf)
{
    const int g  = blockIdx.x >> 1;
    const int hb = blockIdx.x & 1;
    const int w  = threadIdx.x >> 6;
    const int lane = threadIdx.x & 63;
    const int c = lane & 15, q = lane >> 4;

    __shared__ float ptl[16][240];                 // ptab transposed [head][idx]
    __shared__ alignas(16) bf16 pl[4][4096];       // per-wave P (64x64), XOR-swizzled

    for (int i = threadIdx.x; i < 3600; i += 256)
        ptl[i & 15][i >> 4] = ptab[i];
    __syncthreads();

    const size_t rowb = (size_t)g * 64;
    bf16* pw = pl[w];

    for (int hh = 0; hh < 2; ++hh) {
        const int head = hb * 8 + hh * 4 + w;
        const bf16* qb = qkv + rowb * 1536 + head * 32;

        // Q A-frags, K B-frags (16B/lane), V B-frags (b16 gather)
        bf16x8 aq[4], bk[4], bv[2][2];
#pragma unroll
        for (int i = 0; i < 4; ++i) {
            aq[i] = *(const bf16x8*)(qb + (size_t)(i * 16 + c) * 1536 + q * 8);
            bk[i] = *(const bf16x8*)(qb + 512 + (size_t)(i * 16 + c) * 1536 + q * 8);
        }
#pragma unroll
        for (int ks = 0; ks < 2; ++ks)
#pragma unroll
            for (int dt = 0; dt < 2; ++dt)
#pragma unroll
                for (int j = 0; j < 8; ++j)
                    bv[ks][dt][j] = qb[1024 + (size_t)(ks * 32 + q * 8 + j) * 1536 + dt * 16 + c];

        // S = Q K^T  (tile (i,j): rows i*16+(q*4+jj), cols j*16+c)
        f32x4_t s[4][4];
#pragma unroll
        for (int i = 0; i < 4; ++i)
#pragma unroll
            for (int j = 0; j < 4; ++j)
                s[i][j] = __builtin_amdgcn_mfma_f32_16x16x32_bf16(aq[i], bk[j],
                          (f32x4_t){0.f, 0.f, 0.f, 0.f}, 0, 0, 0);

        // scale + rel-pos bias + row softmax (rows live in 16-lane groups)
        const float scale = 0.17677669529663687f;  // 1/sqrt(32)
        float inv[4][4];
#pragma unroll
        for (int i = 0; i < 4; ++i)
#pragma unroll
            for (int jj = 0; jj < 4; ++jj) {
                const int n = i * 16 + q * 4 + jj;
                const int na = n >> 3, nu = n & 7;
                float mx = -1e30f;
#pragma unroll
                for (int j = 0; j < 4; ++j) {
                    const int m = j * 16 + c;
                    const int idx = (na - (m >> 3) + 7) * 15 + (nu - (m & 7) + 7);
                    float v = s[i][j][jj] * scale + ptl[head][idx];
                    s[i][j][jj] = v;
                    mx = fmaxf(mx, v);
                }
#pragma unroll
                for (int off = 1; off < 16; off <<= 1) mx = fmaxf(mx, __shfl_xor(mx, off));
                float sum = 0.f;
#pragma unroll
                for (int j = 0; j < 4; ++j) {
                    float e = __expf(s[i][j][jj] - mx);
                    s[i][j][jj] = e; sum += e;
                }
#pragma unroll
                for (int off = 1; off < 16; off <<= 1) sum += __shfl_xor(sum, off);
                inv[i][jj] = 1.0f / sum;
            }

        // P -> LDS (bf16, swizzled: byte ^= (row&7)<<4)
#pragma unroll
        for (int i = 0; i < 4; ++i)
#pragma unroll
            for (int jj = 0; jj < 4; ++jj) {
                const int n = i * 16 + q * 4 + jj;
                const int swz = (n & 7) << 4;
#pragma unroll
                for (int j = 0; j < 4; ++j) {
                    const int m = j * 16 + c;
                    *(bf16*)((char*)pw + n * 128 + ((m * 2) ^ swz)) = (bf16)s[i][j][jj];
                }
            }

        // O = P V  (A-frags from swizzled LDS, row = i*16+c, k = ks*32+q*8..+7)
        f32x4_t o[4][2];
#pragma unroll
        for (int i = 0; i < 4; ++i)
#pragma unroll
            for (int dt = 0; dt < 2; ++dt)
                o[i][dt] = (f32x4_t){0.f, 0.f, 0.f, 0.f};
#pragma unroll
        for (int ks = 0; ks < 2; ++ks)
#pragma unroll
            for (int i = 0; i < 4; ++i) {
                const int n = i * 16 + c;
                bf16x8 ap = *(const bf16x8*)((char*)pw + n * 128 +
                             ((ks * 64 + q * 16) ^ ((n & 7) << 4)));
#pragma unroll
                for (int dt = 0; dt < 2; ++dt)
                    o[i][dt] = __builtin_amdgcn_mfma_f32_16x16x32_bf16(ap, bv[ks][dt], o[i][dt], 0, 0, 0);
            }

        // normalize + store
        bf16* ob = obuf + rowb * 512 + head * 32;
#pragma unroll
        for (int i = 0; i < 4; ++i)
#pragma unroll
            for (int dt = 0; dt < 2; ++dt)
#pragma unroll
                for (int jj = 0; jj < 4; ++jj) {
                    const int n = i * 16 + q * 4 + jj;
                    ob[(size_t)n * 512 + dt * 16 + c] = (bf16)(o[i][dt][jj] * inv[i][jj]);
                }
    }
}

// ================= 256x256 8-phase GEMM, BK=32, 64 KiB LDS =================
// C[M,N] = A[M,K] * Bw[N,K]^T + bias. 8 waves (2M x 4N), per-wave 128x64 out.
// 2 K-tiles (32 each) per iteration, 8 phases; ONE global_load_lds per thread
// per phase; counted vmcnt(2) at p3/p7 (vmcnt(0) at p3 of last iter).
// LDS row = 32 bf16 = 4 slots of 16B; swizzle slot ^= (row>>1)&3 (2-way = free).
// MODE 0: +bias -> bf16 (QKV) | 1: +bias,gelu -> bf16 (MLP1)
// MODE 2: +bias +x, ungroup -> f32 (proj) | 3: +bias +resid -> f32 (MLP2)

// stage one half (128 rows x 32 cols) of a 256-row K=32 tile: 1 load/thread
#define STAGE_P(dstLDS, src, baseRow, ktv, half)                                          \
    do {                                                                                  \
        const int r_ = (half) * 128 + (tid >> 2);                                         \
        const int s_ = (tid & 3) ^ ((tid >> 3) & 3);                                      \
        ASYNC_COPY16(src + (size_t)((baseRow) + r_) * K + (ktv) + s_ * 8,                 \
                     (bf16*)(dstLDS) + (half) * 4096 + (tid & 448) * 8);                  \
    } while (0)

#define LOAD_A(buf, mh)                                                                   \
    do {                                                                                  \
        _Pragma("unroll")                                                                 \
        for (int m_ = 0; m_ < 4; ++m_) {                                                  \
            const int row_ = wrM * 128 + (mh) * 64 + m_ * 16 + (lane & 15);               \
            af[m_] = *(const bf16x8*)((const char*)Al[buf] + row_ * 64 + rdofs);          \
        }                                                                                 \
    } while (0)

#define LOAD_B(dst, buf, nh)                                                              \
    do {                                                                                  \
        _Pragma("unroll")                                                                 \
        for (int n_ = 0; n_ < 2; ++n_) {                                                  \
            const int row_ = wcN * 64 + (nh) * 32 + n_ * 16 + (lane & 15);                \
            bfr[dst][n_] = *(const bf16x8*)((const char*)Bl[buf] + row_ * 64 + rdofs);    \
        }                                                                                 \
    } while (0)

#define MFMA_Q(mh, nh, bsel)                                                              \
    do {                                                                                  \
        __builtin_amdgcn_s_setprio(1);                                                    \
        _Pragma("unroll")                                                                 \
        for (int m_ = 0; m_ < 4; ++m_) {                                                  \
            _Pragma("unroll")                                                             \
            for (int n_ = 0; n_ < 2; ++n_)                                                \
                acc[(mh) * 4 + m_][(nh) * 2 + n_] =                                       \
                    __builtin_amdgcn_mfma_f32_16x16x32_bf16(                              \
                        af[m_], bfr[bsel][n_], acc[(mh) * 4 + m_][(nh) * 2 + n_], 0, 0, 0); \
        }                                                                                 \
        __builtin_amdgcn_s_setprio(0);                                                    \
    } while (0)

#define BAR() __builtin_amdgcn_s_barrier()
#define WAITV(n) asm volatile("s_waitcnt vmcnt(" #n ")" ::: "memory")

template<int MODE, int NBX>
__global__ __launch_bounds__(512, 2)
void gemm8(const bf16* __restrict__ A, const bf16* __restrict__ Bw,
           const float* __restrict__ bias, const float* __restrict__ resid,
           bf16* __restrict__ outb, float* __restrict__ outf,
           int N, int K)
{
    __shared__ alignas(16) bf16 Al[2][256 * 32];
    __shared__ alignas(16) bf16 Bl[2][256 * 32];
    const int tid = threadIdx.x;
    const int lane = tid & 63;
    const int w = tid >> 6;
    const int wrM = w >> 2, wcN = w & 3;
    // read byte offset within a 64B row: slot q=(lane>>4), XOR'd by (row>>1)&3 = (lane>>1)&3
    const int rdofs = (((lane >> 4) * 16) ^ (((lane >> 1) & 3) << 4));

    // XCD-aware block swizzle (nwg % 8 == 0 at all call sites)
    const int bid = blockIdx.y * NBX + blockIdx.x;
    const int nwg = gridDim.y * NBX;
    const int swz = (bid & 7) * (nwg >> 3) + (bid >> 3);
    const int by = swz / NBX;
    const int bx = swz - by * NBX;
    const int rowBase = by * 256;
    const int colBase = bx * 256;

    f32x4_t acc[8][4];
#pragma unroll
    for (int m = 0; m < 8; ++m)
#pragma unroll
        for (int n = 0; n < 4; ++n)
            acc[m][n] = (f32x4_t){0.f, 0.f, 0.f, 0.f};

    bf16x8 af[4];
    bf16x8 bfr[2][2];

    const int niter = K >> 6;  // two 32-wide K-tiles per iteration

    // prologue: tile0 (A+B) and tile1 (B only); tile1 A staged at p0/p1
    STAGE_P(Al[0], A, rowBase, 0, 0);
    STAGE_P(Al[0], A, rowBase, 0, 1);
    STAGE_P(Bl[0], Bw, colBase, 0, 0);
    STAGE_P(Bl[0], Bw, colBase, 0, 1);
    STAGE_P(Bl[1], Bw, colBase, 32, 0);
    STAGE_P(Bl[1], Bw, colBase, 32, 1);
    WAITV(2);   // tile0 landed; tile1 B still in flight (deadline p4)
    BAR();

    for (int it = 0; it < niter; ++it) {
        const int kA1 = (2 * it + 1) * 32;   // tile T+1 A
        const int kT2 = (2 * it + 2) * 32;   // tile T+2
        const int kB3 = (2 * it + 3) * 32;   // tile T+3 B
        const bool last = (it == niter - 1);

        // ---- p0: tile T (buf0), quadrant (0,0) ----
        LOAD_A(0, 0);
        LOAD_B(0, 0, 0);
        STAGE_P(Al[1], A, rowBase, kA1, 0);
        BAR();
        MFMA_Q(0, 0, 0);
        BAR();
        // ---- p1: (0,1) ----
        LOAD_B(1, 0, 1);
        STAGE_P(Al[1], A, rowBase, kA1, 1);
        BAR();
        MFMA_Q(0, 1, 1);
        BAR();
        // ---- p2: (1,0) ----
        LOAD_A(0, 1);
        if (!last) STAGE_P(Bl[0], Bw, colBase, kT2, 0);
        BAR();
        MFMA_Q(1, 0, 0);
        BAR();
        // ---- p3: (1,1) ----
        if (!last) STAGE_P(Bl[0], Bw, colBase, kT2, 1);
        BAR();
        MFMA_Q(1, 1, 1);
        if (last) { WAITV(0); } else { WAITV(2); }   // buf1 (tile T+1) complete
        BAR();

        // ---- p4: tile T+1 (buf1), quadrant (0,0) ----
        LOAD_A(1, 0);
        LOAD_B(0, 1, 0);
        if (!last) STAGE_P(Al[0], A, rowBase, kT2, 0);
        BAR();
        MFMA_Q(0, 0, 0);
        BAR();
        // ---- p5: (0,1) ----
        LOAD_B(1, 1, 1);
        if (!last) STAGE_P(Al[0], A, rowBase, kT2, 1);
        BAR();
        MFMA_Q(0, 1, 1);
        BAR();
        // ---- p6: (1,0) ----
        LOAD_A(1, 1);
        if (!last) STAGE_P(Bl[1], Bw, colBase, kB3, 0);
        BAR();
        MFMA_Q(1, 0, 0);
        BAR();
        // ---- p7: (1,1) ----
        if (!last) STAGE_P(Bl[1], Bw, colBase, kB3, 1);
        BAR();
        MFMA_Q(1, 1, 1);
        if (!last) { WAITV(2); }                     // buf0 (tile T+2) complete
        BAR();
    }

    // epilogue
#pragma unroll
    for (int m = 0; m < 8; ++m) {
#pragma unroll
        for (int jj = 0; jj < 4; ++jj) {
            int grow = rowBase + wrM * 128 + m * 16 + (lane >> 4) * 4 + jj;
#pragma unroll
            for (int n = 0; n < 4; ++n) {
                int gcol = colBase + wcN * 64 + n * 16 + (lane & 15);
                float v = acc[m][n][jj] + bias[gcol];
                if constexpr (MODE == 0) {
                    outb[(size_t)grow * N + gcol] = (bf16)v;
                } else if constexpr (MODE == 1) {
                    float e = __expf(1.5957691216057308f * (v + 0.044715f * v * v * v));
                    v = v * (e / (1.0f + e));
                    outb[(size_t)grow * N + gcol] = (bf16)v;
                } else if constexpr (MODE == 2) {
                    int g = grow >> 6, ns = grow & 63;
                    int b = g >> 6, i = (g >> 3) & 7, j = g & 7;
                    int a = ns >> 3, u = ns & 7;
                    int t = b * 4096 + (a * 8 + i) * 64 + (u * 8 + j);
                    size_t oi = (size_t)t * 512 + gcol;
                    outf[oi] = resid[oi] + v;
                } else {
                    size_t oi = (size_t)grow * 512 + gcol;
                    outf[oi] = resid[oi] + v;
                }
            }
        }
    }
}

// ---------------- launcher ----------------
extern "C" void kernel_launch(void* const* d_in, const int* in_sizes, int n_in,
                              void* d_out, int out_size, void* d_ws, size_t ws_size,
                              hipStream_t stream)
{
    const float* x    = (const float*)d_in[0];
    const float* n1g  = (const float*)d_in[1];
    const float* n1b  = (const float*)d_in[2];
    const float* qkvw = (const float*)d_in[3];
    const float* qkvb = (const float*)d_in[4];
    const float* pjw  = (const float*)d_in[5];
    const float* pjb  = (const float*)d_in[6];
    const float* pw0  = (const float*)d_in[7];
    const float* pb0  = (const float*)d_in[8];
    const float* pg0  = (const float*)d_in[9];
    const float* pbb0 = (const float*)d_in[10];
    const float* pw1  = (const float*)d_in[11];
    const float* pb1  = (const float*)d_in[12];
    const float* pg1  = (const float*)d_in[13];
    const float* pbb1 = (const float*)d_in[14];
    const float* pw2  = (const float*)d_in[15];
    const float* pb2  = (const float*)d_in[16];
    const float* pg2  = (const float*)d_in[17];
    const float* pbb2 = (const float*)d_in[18];
    const float* pw3  = (const float*)d_in[19];
    const float* pb3  = (const float*)d_in[20];
    const float* n2g  = (const float*)d_in[21];
    const float* n2b  = (const float*)d_in[22];
    const float* w1   = (const float*)d_in[23];
    const float* b1   = (const float*)d_in[24];
    const float* w2   = (const float*)d_in[25];
    const float* b2   = (const float*)d_in[26];

    char* ws = (char*)d_ws;
    bf16* qkvw_b = (bf16*)(ws + OFF_QKVW);
    bf16* pjw_b  = (bf16*)(ws + OFF_PROJW);
    bf16* w1_b   = (bf16*)(ws + OFF_W1);
    bf16* w2_b   = (bf16*)(ws + OFF_W2);
    float* ptab  = (float*)(ws + OFF_PTAB);
    bf16* bufA   = (bf16*)(ws + OFF_A);
    bf16* bufB   = (bf16*)(ws + OFF_B);
    float* xout  = (float*)d_out;

    // weight casts
    cast_bf16_k<<<(1536 * 512 / 4 + 255) / 256, 256, 0, stream>>>(qkvw, qkvw_b, 1536 * 512 / 4);
    cast_bf16_k<<<(512 * 512 / 4 + 255) / 256, 256, 0, stream>>>(pjw, pjw_b, 512 * 512 / 4);
    cast_bf16_k<<<(2048 * 512 / 4 + 255) / 256, 256, 0, stream>>>(w1, w1_b, 2048 * 512 / 4);
    cast_bf16_k<<<(512 * 2048 / 4 + 255) / 256, 256, 0, stream>>>(w2, w2_b, 512 * 2048 / 4);

    // pos-bias table
    posmlp_k<<<1, 256, 0, stream>>>(pw0, pb0, pg0, pbb0, pw1, pb1, pg1, pbb1,
                                    pw2, pb2, pg2, pbb2, pw3, pb3, ptab);

    // LN1 + group -> bufB
    ln_k<1><<<16384, 256, 0, stream>>>(x, n1g, n1b, bufB);

    // QKV -> bufA   (M=65536 -> 256 row blocks)
    gemm8<0, 6><<<dim3(6, 256), 512, 0, stream>>>(bufB, qkvw_b, qkvb, nullptr, bufA, nullptr, 1536, 512);

    // attention -> bufB
    attn_mfma_k<<<2048, 256, 0, stream>>>(bufA, ptab, bufB);

    // proj + ungroup + residual(x) -> d_out (x1)
    gemm8<2, 2><<<dim3(2, 256), 512, 0, stream>>>(bufB, pjw_b, pjb, x, nullptr, xout, 512, 512);

    // LN2 -> bufB
    ln_k<0><<<16384, 256, 0, stream>>>(xout, n2g, n2b, bufB);

    // MLP1 + gelu -> bufA
    gemm8<1, 8><<<dim3(8, 256), 512, 0, stream>>>(bufB, w1_b, b1, nullptr, bufA, nullptr, 2048, 512);

    // MLP2 + residual(x1) -> d_out (in place)
    gemm8<3, 2><<<dim3(2, 256), 512, 0, stream>>>(bufA, w2_b, b2, xout, nullptr, xout, 512, 2048);
}

// Round 7
// 890.856 us; speedup vs baseline: 1.2233x; 1.2233x over previous
//
#include <hip/hip_runtime.h>
#include <hip/hip_bf16.h>

typedef __bf16 bf16;
typedef __bf16 bf16x8 __attribute__((ext_vector_type(8)));
typedef __bf16 bf16x4 __attribute__((ext_vector_type(4)));
typedef float f32x4_t __attribute__((ext_vector_type(4)));

static constexpr int kDIM = 512;

// ---------------- ws layout (bytes) ----------------
static constexpr size_t OFF_QKVW = 0;                         // 1536*512 bf16
static constexpr size_t OFF_PROJW = 1572864;                  // 512*512 bf16
static constexpr size_t OFF_W1   = 2097152;                   // 2048*512 bf16
static constexpr size_t OFF_W2   = 4194304;                   // 512*2048 bf16
static constexpr size_t OFF_PTAB = 6291456;                   // 225*16 f32
static constexpr size_t OFF_A    = 8388608;                   // qkv / hidden bf16
static constexpr size_t OFF_B    = 276824064;                 // h / o / ln2out bf16

typedef __attribute__((address_space(3))) uint32_t lds_u32_t;
typedef __attribute__((address_space(1))) const uint32_t glb_u32_t;
#define ASYNC_COPY16(gp, lp) __builtin_amdgcn_global_load_lds((glb_u32_t*)(gp), (lds_u32_t*)(lp), 16, 0, 0)
#define WAITV0() asm volatile("s_waitcnt vmcnt(0)" ::: "memory")

// ---------------- fp32 -> bf16 cast ----------------
__global__ void cast_bf16_k(const float* __restrict__ in, bf16* __restrict__ out, int n4)
{
    int i = blockIdx.x * blockDim.x + threadIdx.x;
    if (i < n4) {
        float4 v = ((const float4*)in)[i];
        bf16x4 o; o[0] = (bf16)v.x; o[1] = (bf16)v.y; o[2] = (bf16)v.z; o[3] = (bf16)v.w;
        ((bf16x4*)out)[i] = o;
    }
}

// ---------------- LayerNorm (+ optional LDA grouping) -> bf16 ----------------
template<int GROUP>
__global__ __launch_bounds__(256)
void ln_k(const float* __restrict__ x, const float* __restrict__ gw,
          const float* __restrict__ bw, bf16* __restrict__ out)
{
    const int t = blockIdx.x * 4 + (threadIdx.x >> 6);
    const int lane = threadIdx.x & 63;
    const float* xp = x + (size_t)t * kDIM + lane * 8;
    float4 p0 = *(const float4*)xp;
    float4 p1 = *(const float4*)(xp + 4);
    float v[8] = {p0.x, p0.y, p0.z, p0.w, p1.x, p1.y, p1.z, p1.w};
    float s = 0.f;
#pragma unroll
    for (int i = 0; i < 8; ++i) s += v[i];
#pragma unroll
    for (int off = 32; off > 0; off >>= 1) s += __shfl_xor(s, off);
    const float mean = s * (1.0f / 512.0f);
    float q = 0.f;
#pragma unroll
    for (int i = 0; i < 8; ++i) { float d = v[i] - mean; q += d * d; }
#pragma unroll
    for (int off = 32; off > 0; off >>= 1) q += __shfl_xor(q, off);
    const float rstd = rsqrtf(q * (1.0f / 512.0f) + 1e-5f);
    size_t orow;
    if (GROUP) {
        int b = t >> 12, r = (t >> 6) & 63, c = t & 63;
        int g = b * 64 + (r & 7) * 8 + (c & 7);
        int n = (r >> 3) * 8 + (c >> 3);
        orow = (size_t)g * 64 + n;
    } else {
        orow = t;
    }
    float4 g0 = *(const float4*)(gw + lane * 8);
    float4 g1 = *(const float4*)(gw + lane * 8 + 4);
    float4 b0 = *(const float4*)(bw + lane * 8);
    float4 b1 = *(const float4*)(bw + lane * 8 + 4);
    float gg[8] = {g0.x, g0.y, g0.z, g0.w, g1.x, g1.y, g1.z, g1.w};
    float bb[8] = {b0.x, b0.y, b0.z, b0.w, b1.x, b1.y, b1.z, b1.w};
    bf16x8 o8;
#pragma unroll
    for (int i = 0; i < 8; ++i) o8[i] = (bf16)((v[i] - mean) * rstd * gg[i] + bb[i]);
    *(bf16x8*)(out + orow * kDIM + lane * 8) = o8;
}

// ---------------- dynamic position bias MLP: 225 rows, 2->32->32->32->16 ----------------
__device__ inline void ln32_relu(float* h, const float* g, const float* b)
{
    float m = 0.f;
#pragma unroll
    for (int i = 0; i < 32; ++i) m += h[i];
    m *= (1.0f / 32.0f);
    float v = 0.f;
#pragma unroll
    for (int i = 0; i < 32; ++i) { float d = h[i] - m; v += d * d; }
    v *= (1.0f / 32.0f);
    float r = rsqrtf(v + 1e-5f);
#pragma unroll
    for (int i = 0; i < 32; ++i) h[i] = fmaxf((h[i] - m) * r * g[i] + b[i], 0.f);
}

__global__ __launch_bounds__(256)
void posmlp_k(const float* __restrict__ w0, const float* __restrict__ b0,
              const float* __restrict__ g0, const float* __restrict__ bb0,
              const float* __restrict__ w1, const float* __restrict__ b1,
              const float* __restrict__ g1, const float* __restrict__ bb1,
              const float* __restrict__ w2, const float* __restrict__ b2,
              const float* __restrict__ g2, const float* __restrict__ bb2,
              const float* __restrict__ w3, const float* __restrict__ b3,
              float* __restrict__ ptab)
{
    int r = threadIdx.x;
    if (r >= 225) return;
    float in0 = (float)(r / 15) - 7.0f;
    float in1 = (float)(r % 15) - 7.0f;
    float h[32], h2[32];
#pragma unroll
    for (int o = 0; o < 32; ++o) h[o] = w0[o * 2] * in0 + w0[o * 2 + 1] * in1 + b0[o];
    ln32_relu(h, g0, bb0);
#pragma unroll
    for (int o = 0; o < 32; ++o) {
        float s = b1[o];
#pragma unroll
        for (int i = 0; i < 32; ++i) s += w1[o * 32 + i] * h[i];
        h2[o] = s;
    }
    ln32_relu(h2, g1, bb1);
#pragma unroll
    for (int o = 0; o < 32; ++o) {
        float s = b2[o];
#pragma unroll
        for (int i = 0; i < 32; ++i) s += w2[o * 32 + i] * h2[i];
        h[o] = s;
    }
    ln32_relu(h, g2, bb2);
#pragma unroll
    for (int o = 0; o < 16; ++o) {
        float s = b3[o];
#pragma unroll
        for (int i = 0; i < 32; ++i) s += w3[o * 32 + i] * h[i];
        ptab[r * 16 + o] = s;
    }
}

// ---------------- attention via MFMA: block = (group, head-octet), 4 waves x 2 heads ----------------
__global__ __launch_bounds__(256)
void attn_mfma_k(const bf16* __restrict__ qkv, const float* __restrict__ ptab,
                 bf16* __restrict__ obuf)
{
    const int g  = blockIdx.x >> 1;
    const int hb = blockIdx.x & 1;
    const int w  = threadIdx.x >> 6;
    const int lane = threadIdx.x & 63;
    const int c = lane & 15, q = lane >> 4;

    __shared__ float ptl[16][240];                 // ptab transposed [head][idx]
    __shared__ alignas(16) bf16 pl[4][4096];       // per-wave P (64x64), XOR-swizzled

    for (int i = threadIdx.x; i < 3600; i += 256)
        ptl[i & 15][i >> 4] = ptab[i];
    __syncthreads();

    const size_t rowb = (size_t)g * 64;
    bf16* pw = pl[w];

    for (int hh = 0; hh < 2; ++hh) {
        const int head = hb * 8 + hh * 4 + w;
        const bf16* qb = qkv + rowb * 1536 + head * 32;

        // Q A-frags, K B-frags (16B/lane), V B-frags (b16 gather)
        bf16x8 aq[4], bk[4], bv[2][2];
#pragma unroll
        for (int i = 0; i < 4; ++i) {
            aq[i] = *(const bf16x8*)(qb + (size_t)(i * 16 + c) * 1536 + q * 8);
            bk[i] = *(const bf16x8*)(qb + 512 + (size_t)(i * 16 + c) * 1536 + q * 8);
        }
#pragma unroll
        for (int ks = 0; ks < 2; ++ks)
#pragma unroll
            for (int dt = 0; dt < 2; ++dt)
#pragma unroll
                for (int j = 0; j < 8; ++j)
                    bv[ks][dt][j] = qb[1024 + (size_t)(ks * 32 + q * 8 + j) * 1536 + dt * 16 + c];

        // S = Q K^T  (tile (i,j): rows i*16+(q*4+jj), cols j*16+c)
        f32x4_t s[4][4];
#pragma unroll
        for (int i = 0; i < 4; ++i)
#pragma unroll
            for (int j = 0; j < 4; ++j)
                s[i][j] = __builtin_amdgcn_mfma_f32_16x16x32_bf16(aq[i], bk[j],
                          (f32x4_t){0.f, 0.f, 0.f, 0.f}, 0, 0, 0);

        // scale + rel-pos bias + row softmax (rows live in 16-lane groups)
        const float scale = 0.17677669529663687f;  // 1/sqrt(32)
        float inv[4][4];
#pragma unroll
        for (int i = 0; i < 4; ++i)
#pragma unroll
            for (int jj = 0; jj < 4; ++jj) {
                const int n = i * 16 + q * 4 + jj;
                const int na = n >> 3, nu = n & 7;
                float mx = -1e30f;
#pragma unroll
                for (int j = 0; j < 4; ++j) {
                    const int m = j * 16 + c;
                    const int idx = (na - (m >> 3) + 7) * 15 + (nu - (m & 7) + 7);
                    float v = s[i][j][jj] * scale + ptl[head][idx];
                    s[i][j][jj] = v;
                    mx = fmaxf(mx, v);
                }
#pragma unroll
                for (int off = 1; off < 16; off <<= 1) mx = fmaxf(mx, __shfl_xor(mx, off));
                float sum = 0.f;
#pragma unroll
                for (int j = 0; j < 4; ++j) {
                    float e = __expf(s[i][j][jj] - mx);
                    s[i][j][jj] = e; sum += e;
                }
#pragma unroll
                for (int off = 1; off < 16; off <<= 1) sum += __shfl_xor(sum, off);
                inv[i][jj] = 1.0f / sum;
            }

        // P -> LDS (bf16, swizzled: byte ^= (row&7)<<4)
#pragma unroll
        for (int i = 0; i < 4; ++i)
#pragma unroll
            for (int jj = 0; jj < 4; ++jj) {
                const int n = i * 16 + q * 4 + jj;
                const int swz = (n & 7) << 4;
#pragma unroll
                for (int j = 0; j < 4; ++j) {
                    const int m = j * 16 + c;
                    *(bf16*)((char*)pw + n * 128 + ((m * 2) ^ swz)) = (bf16)s[i][j][jj];
                }
            }

        // O = P V  (A-frags from swizzled LDS, row = i*16+c, k = ks*32+q*8..+7)
        f32x4_t o[4][2];
#pragma unroll
        for (int i = 0; i < 4; ++i)
#pragma unroll
            for (int dt = 0; dt < 2; ++dt)
                o[i][dt] = (f32x4_t){0.f, 0.f, 0.f, 0.f};
#pragma unroll
        for (int ks = 0; ks < 2; ++ks)
#pragma unroll
            for (int i = 0; i < 4; ++i) {
                const int n = i * 16 + c;
                bf16x8 ap = *(const bf16x8*)((char*)pw + n * 128 +
                             ((ks * 64 + q * 16) ^ ((n & 7) << 4)));
#pragma unroll
                for (int dt = 0; dt < 2; ++dt)
                    o[i][dt] = __builtin_amdgcn_mfma_f32_16x16x32_bf16(ap, bv[ks][dt], o[i][dt], 0, 0, 0);
            }

        // normalize + store
        bf16* ob = obuf + rowb * 512 + head * 32;
#pragma unroll
        for (int i = 0; i < 4; ++i)
#pragma unroll
            for (int dt = 0; dt < 2; ++dt)
#pragma unroll
                for (int jj = 0; jj < 4; ++jj) {
                    const int n = i * 16 + q * 4 + jj;
                    ob[(size_t)n * 512 + dt * 16 + c] = (bf16)(o[i][dt][jj] * inv[i][jj]);
                }
    }
}

// ---------------- GEMM: C[M,N] = A[M,K] * Bw[N,K]^T + bias ----------------
// Round-2 proven structure: 128x128 tile, BK=64, single LDS buffer, 2 barriers/iter,
// global_load_lds staging. Race closed via EXPLICIT vmcnt(0) before the post-stage
// barrier (RAW); the post-compute barrier orders reads-done before next DMA (WAR).
// T2: bank-conflict-free via pre-swizzled global source (slot s -> s^(row&7)), LDS
//     dest linear; reads XOR the same involution -> 2-way aliasing only (free).
// T1: XCD-aware bijective block swizzle (all grids have nwg % 8 == 0).
// MODE 0: +bias -> bf16 (QKV) | 1: +bias,gelu -> bf16 (MLP1)
// MODE 2: +bias +x, ungroup -> f32 (proj) | 3: +bias +resid -> f32 (MLP2)
template<int MODE, int NBX>
__global__ __launch_bounds__(256, 2)
void gemm_bt(const bf16* __restrict__ A, const bf16* __restrict__ Bw,
             const float* __restrict__ bias, const float* __restrict__ resid,
             bf16* __restrict__ outb, float* __restrict__ outf,
             int N, int K)
{
    __shared__ alignas(16) bf16 As[128 * 64];
    __shared__ alignas(16) bf16 Bs[128 * 64];
    const int tid = threadIdx.x;
    const int lane = tid & 63;
    const int w = tid >> 6;
    const int wr = w >> 1, wc = w & 1;

    // T1: XCD swizzle, bijective since nwg % 8 == 0
    const int bid = blockIdx.y * NBX + blockIdx.x;
    const int nwg = gridDim.y * NBX;
    const int swz = (bid & 7) * (nwg >> 3) + (bid >> 3);
    const int by = swz / NBX;
    const int bx = swz - by * NBX;
    const int rowBase = by * 128;
    const int colBase = bx * 128;

    f32x4_t acc[4][4];
#pragma unroll
    for (int m = 0; m < 4; ++m)
#pragma unroll
        for (int n = 0; n < 4; ++n)
            acc[m][n] = (f32x4_t){0.f, 0.f, 0.f, 0.f};

    const int sw = (lane & 7) << 4;  // read-side XOR: (row&7)<<4, row&7 == lane&7

    for (int kt = 0; kt < K; kt += 64) {
        // stage: LDS dest linear (wave-uniform base + lane*16), SOURCE pre-swizzled
#pragma unroll
        for (int l = 0; l < 4; ++l) {
            const int cg = l * 256 + tid;
            const int row = cg >> 3;
            const int col8 = (cg & 7) ^ (row & 7);
            const int cu = l * 256 + (tid & 192);        // wave-uniform LDS base
            ASYNC_COPY16(A + (size_t)(rowBase + row) * K + kt + col8 * 8, As + cu * 8);
            ASYNC_COPY16(Bw + (size_t)(colBase + row) * K + kt + col8 * 8, Bs + cu * 8);
        }
        WAITV0();             // explicit RAW drain: all DMA landed in LDS
        __syncthreads();
#pragma unroll
        for (int kk = 0; kk < 64; kk += 32) {
            const int bofs = kk * 2 + (lane >> 4) * 16;  // byte slot within 128B row
            bf16x8 af[4], bfr[4];
#pragma unroll
            for (int m = 0; m < 4; ++m) {
                const int row = wr * 64 + m * 16 + (lane & 15);
                af[m] = *(const bf16x8*)((const char*)As + row * 128 + (bofs ^ sw));
            }
#pragma unroll
            for (int n = 0; n < 4; ++n) {
                const int row = wc * 64 + n * 16 + (lane & 15);
                bfr[n] = *(const bf16x8*)((const char*)Bs + row * 128 + (bofs ^ sw));
            }
#pragma unroll
            for (int m = 0; m < 4; ++m)
#pragma unroll
                for (int n = 0; n < 4; ++n)
                    acc[m][n] = __builtin_amdgcn_mfma_f32_16x16x32_bf16(af[m], bfr[n], acc[m][n], 0, 0, 0);
        }
        __syncthreads();      // WAR: all reads done before next iteration's DMA
    }

#pragma unroll
    for (int m = 0; m < 4; ++m) {
#pragma unroll
        for (int jj = 0; jj < 4; ++jj) {
            int grow = rowBase + wr * 64 + m * 16 + (lane >> 4) * 4 + jj;
#pragma unroll
            for (int n = 0; n < 4; ++n) {
                int gcol = colBase + wc * 64 + n * 16 + (lane & 15);
                float v = acc[m][n][jj] + bias[gcol];
                if constexpr (MODE == 0) {
                    outb[(size_t)grow * N + gcol] = (bf16)v;
                } else if constexpr (MODE == 1) {
                    // gelu(v) ~= v * sigmoid(1.5957691*(v + 0.044715 v^3))
                    float e = __expf(1.5957691216057308f * (v + 0.044715f * v * v * v));
                    v = v * (e / (1.0f + e));
                    outb[(size_t)grow * N + gcol] = (bf16)v;
                } else if constexpr (MODE == 2) {
                    int g = grow >> 6, ns = grow & 63;
                    int b = g >> 6, i = (g >> 3) & 7, j = g & 7;
                    int a = ns >> 3, u = ns & 7;
                    int t = b * 4096 + (a * 8 + i) * 64 + (u * 8 + j);
                    size_t oi = (size_t)t * 512 + gcol;
                    outf[oi] = resid[oi] + v;
                } else {
                    size_t oi = (size_t)grow * 512 + gcol;
                    outf[oi] = resid[oi] + v;
                }
            }
        }
    }
}

// ---------------- launcher ----------------
extern "C" void kernel_launch(void* const* d_in, const int* in_sizes, int n_in,
                              void* d_out, int out_size, void* d_ws, size_t ws_size,
                              hipStream_t stream)
{
    const float* x    = (const float*)d_in[0];
    const float* n1g  = (const float*)d_in[1];
    const float* n1b  = (const float*)d_in[2];
    const float* qkvw = (const float*)d_in[3];
    const float* qkvb = (const float*)d_in[4];
    const float* pjw  = (const float*)d_in[5];
    const float* pjb  = (const float*)d_in[6];
    const float* pw0  = (const float*)d_in[7];
    const float* pb0  = (const float*)d_in[8];
    const float* pg0  = (const float*)d_in[9];
    const float* pbb0 = (const float*)d_in[10];
    const float* pw1  = (const float*)d_in[11];
    const float* pb1  = (const float*)d_in[12];
    const float* pg1  = (const float*)d_in[13];
    const float* pbb1 = (const float*)d_in[14];
    const float* pw2  = (const float*)d_in[15];
    const float* pb2  = (const float*)d_in[16];
    const float* pg2  = (const float*)d_in[17];
    const float* pbb2 = (const float*)d_in[18];
    const float* pw3  = (const float*)d_in[19];
    const float* pb3  = (const float*)d_in[20];
    const float* n2g  = (const float*)d_in[21];
    const float* n2b  = (const float*)d_in[22];
    const float* w1   = (const float*)d_in[23];
    const float* b1   = (const float*)d_in[24];
    const float* w2   = (const float*)d_in[25];
    const float* b2   = (const float*)d_in[26];

    char* ws = (char*)d_ws;
    bf16* qkvw_b = (bf16*)(ws + OFF_QKVW);
    bf16* pjw_b  = (bf16*)(ws + OFF_PROJW);
    bf16* w1_b   = (bf16*)(ws + OFF_W1);
    bf16* w2_b   = (bf16*)(ws + OFF_W2);
    float* ptab  = (float*)(ws + OFF_PTAB);
    bf16* bufA   = (bf16*)(ws + OFF_A);
    bf16* bufB   = (bf16*)(ws + OFF_B);
    float* xout  = (float*)d_out;

    // weight casts
    cast_bf16_k<<<(1536 * 512 / 4 + 255) / 256, 256, 0, stream>>>(qkvw, qkvw_b, 1536 * 512 / 4);
    cast_bf16_k<<<(512 * 512 / 4 + 255) / 256, 256, 0, stream>>>(pjw, pjw_b, 512 * 512 / 4);
    cast_bf16_k<<<(2048 * 512 / 4 + 255) / 256, 256, 0, stream>>>(w1, w1_b, 2048 * 512 / 4);
    cast_bf16_k<<<(512 * 2048 / 4 + 255) / 256, 256, 0, stream>>>(w2, w2_b, 512 * 2048 / 4);

    // pos-bias table
    posmlp_k<<<1, 256, 0, stream>>>(pw0, pb0, pg0, pbb0, pw1, pb1, pg1, pbb1,
                                    pw2, pb2, pg2, pbb2, pw3, pb3, ptab);

    // LN1 + group -> bufB
    ln_k<1><<<16384, 256, 0, stream>>>(x, n1g, n1b, bufB);

    // QKV -> bufA
    gemm_bt<0, 12><<<dim3(12, 512), 256, 0, stream>>>(bufB, qkvw_b, qkvb, nullptr, bufA, nullptr, 1536, 512);

    // attention -> bufB
    attn_mfma_k<<<2048, 256, 0, stream>>>(bufA, ptab, bufB);

    // proj + ungroup + residual(x) -> d_out (x1)
    gemm_bt<2, 4><<<dim3(4, 512), 256, 0, stream>>>(bufB, pjw_b, pjb, x, nullptr, xout, 512, 512);

    // LN2 -> bufB
    ln_k<0><<<16384, 256, 0, stream>>>(xout, n2g, n2b, bufB);

    // MLP1 + gelu -> bufA
    gemm_bt<1, 16><<<dim3(16, 512), 256, 0, stream>>>(bufB, w1_b, b1, nullptr, bufA, nullptr, 2048, 512);

    // MLP2 + residual(x1) -> d_out (in place)
    gemm_bt<3, 4><<<dim3(4, 512), 256, 0, stream>>>(bufA, w2_b, b2, xout, nullptr, xout, 512, 2048);
}